// Round 12
// baseline (18546.011 us; speedup 1.0000x reference)
//
#include <hip/hip_runtime.h>
#include <hip/hip_bf16.h>

// 5-layer LSTM, B=64, T=256, H=1024. bf16 MFMA (16x16x32), fp32 state.
// Round 12: hybrid of r6 (8 waves = 2/SIMD latency hiding) and r8 (swapped
// MFMA, lane-local epilogue, ZERO t-loop barriers):
//  - 128 blocks x 512 threads; block = FULL batch (64 rows) x 8 units
//  - waves: ms = w&3 (16-row slice), nt = w>>2 (4-unit half); lane owns
//    (row = 16ms + l15, unit = 8cb + 4nt + lhi); acc[j] = gate j
//  - weights: r8's 128 KiB fragment-linear LDS slab (0 bank conflicts, r10)
//  - per-wave u16 flags, 256-flag groups per ms; nothing between h-store's
//    vmcnt(0) and the flag store (r11 lesson)

using bf16x8 = __attribute__((ext_vector_type(8))) __bf16;
using f32x4  = __attribute__((ext_vector_type(4))) float;
using u32x2  = __attribute__((ext_vector_type(2))) unsigned;

#define Tn 256
#define Bn 64
#define Hn 1024

#define MFMA16(a, b, c) __builtin_amdgcn_mfma_f32_16x16x32_bf16((a), (b), (c), 0, 0, 0)

// ---------------------------------------------------------------------------
// r8's convW, verbatim (produced bit-correct results in r8):
// Wg[l][k][unit] fp32 -> Wperm A-frag-linear bf16.
// Per (l,cb) a 128 KiB slab of 128 frags x 64 lanes x 16 B.
// frag = (p*2+nt)*32 + kt   (p: 0=x,1=h; nt: unit sub-block; kt: K/32 step)
// lane = lhi*16 + c16, c16 = u4*4 + g  (gate g in A-row bits -> D-row j)
// element (gate-col c16 of unit cb*8+nt*4+u4, k = p*1024 + kt*32 + lhi*8 + j)
__global__ void convW(const float* __restrict__ Wi, const float* __restrict__ Wf,
                      const float* __restrict__ Wc, const float* __restrict__ Wo,
                      __bf16* __restrict__ Wperm) {
    int gid = blockIdx.x * 256 + threadIdx.x;      // 5*1024*4*256 = 5,242,880
    int k8   = gid & 255;                          // 8-k chunk: k = k8*8
    int g    = (gid >> 8) & 3;
    int unit = (gid >> 10) & 1023;
    int l    = gid >> 20;
    const float* Wg = (g == 0) ? Wi : (g == 1) ? Wf : (g == 2) ? Wc : Wo;
    const float* src = Wg + ((size_t)l * 2048 + k8 * 8) * 1024 + unit;
    bf16x8 v;
#pragma unroll
    for (int j = 0; j < 8; ++j) v[j] = (__bf16)src[(size_t)j * 1024];
    int cb = unit >> 3, nt = (unit >> 2) & 1, u4 = unit & 3;
    int c16 = u4 * 4 + g;
    int p = k8 >> 7, kt = (k8 >> 2) & 31, lhi = k8 & 3;
    int lane = lhi * 16 + c16;
    int frag = (p * 2 + nt) * 32 + kt;
    size_t dst = ((size_t)(l * 128 + cb) * 128 + frag) * 1024 + lane * 16;
    *(bf16x8*)((char*)Wperm + dst) = v;
}

// x[b][t][k] fp32 -> seq[t][b][k] bf16
__global__ void convX(const float* __restrict__ x, __bf16* __restrict__ seq) {
    int gid = blockIdx.x * 256 + threadIdx.x;      // 2,097,152
    int k8 = gid & 127;
    int b  = (gid >> 7) & 63;
    int t  = gid >> 13;
    const float* src = x + ((size_t)b * Tn + t) * Hn + k8 * 8;
    bf16x8 v;
#pragma unroll
    for (int j = 0; j < 8; ++j) v[j] = (__bf16)src[j];
    *(bf16x8*)(seq + (size_t)gid * 8) = v;
}

// ---------------------------------------------------------------------------
__device__ __forceinline__ void store_coh_u32x2(void* p, u32x2 v) {
    asm volatile("global_store_dwordx2 %0, %1, off sc0 sc1" :: "v"(p), "v"(v) : "memory");
}
__device__ __forceinline__ void store_coh_u16(void* p, unsigned v) {
    asm volatile("global_store_short %0, %1, off sc0 sc1" :: "v"(p), "v"(v) : "memory");
}

// poll own 256-flag group (u16 each), 4 flags/lane; first try sleep-free
__device__ __forceinline__ void pollwait(const char* p, unsigned target) {
    while (true) {
        u32x2 v;
        asm volatile("global_load_dwordx2 %0, %1, off sc0 sc1\n\ts_waitcnt vmcnt(0)"
                     : "=&v"(v) : "v"(p) : "memory");
        unsigned w0 = v[0], w1 = v[1];
        bool ok = ((w0 & 0xFFFFu) >= target) && ((w0 >> 16) >= target) &&
                  ((w1 & 0xFFFFu) >= target) && ((w1 >> 16) >= target);
        if (__all((int)ok)) break;
        __builtin_amdgcn_s_sleep(1);
    }
}

// fast gates: v_exp_f32 computes 2^x; v_rcp_f32 ~1ulp
__device__ __forceinline__ float fsigmoid(float z) {
    return __builtin_amdgcn_rcpf(1.f + __builtin_amdgcn_exp2f(-1.44269504089f * z));
}
__device__ __forceinline__ float ftanh(float z) {
    return 1.f - 2.f * __builtin_amdgcn_rcpf(1.f + __builtin_amdgcn_exp2f(2.88539008178f * z));
}

// ---------------------------------------------------------------------------
// Persistent kernel. 128 blocks x 512 threads (8 waves = 2/SIMD), 1 block/CU.
// Block cb: units [8cb, 8cb+8), FULL batch. Wave w: ms = w&3 (rows
// [16ms,16ms+16)), nt = w>>2 (units [8cb+4nt, +4)). Lane: row = 16ms+l15,
// unit = 8cb+4nt+lhi; acc[j] = gate j (i,f,g,o).
// Flags: u16 at index ms*256 + cb*2 + nt; consumer wave ms polls its own
// 256-u16 group (512 B, 8 B/lane). No __syncthreads in the t-loop.
// LDS: [0,131072) weight slab, fragment-linear (frag = (p*2+nt)*32+kt).
__global__ __launch_bounds__(512, 2) void lstm_all(
    __bf16* __restrict__ seqA, __bf16* __restrict__ seqB,
    const __bf16* __restrict__ Wperm,
    const float* __restrict__ bip, const float* __restrict__ bfp,
    const float* __restrict__ bcp, const float* __restrict__ bop,
    unsigned short* __restrict__ bar) {
    extern __shared__ char smem[];                 // 128 KiB weight slab

    const int tid  = threadIdx.x;
    const int cb   = blockIdx.x;
    const int w    = tid >> 6;
    const int lane = tid & 63;
    const int ms   = w & 3;
    const int nt   = w >> 2;
    const int l15  = lane & 15;
    const int lhi  = lane >> 4;
    const int row  = ms * 16 + l15;                // batch row (B-frag col)
    const unsigned lane16 = (unsigned)lane << 4;

    unsigned short* myflag = bar + ms * 256 + cb * 2 + nt;
    const char* pollp = (const char*)bar + ms * 512 + lane * 8;

    __bf16* inp  = seqA;
    __bf16* outp = seqB;

    for (int l = 0; l < 5; ++l) {
        __syncthreads();                           // old slab no longer read
        pollwait(pollp, (unsigned)(l * Tn));       // prev layer complete (l=0 trivial)
        __builtin_amdgcn_fence(__ATOMIC_ACQUIRE, "agent");   // inv L1/L2

        // ---- stage this layer's 128 KiB slab into LDS
        const char* Wl = (const char*)Wperm + (size_t)(l * 128 + cb) * 131072;
#pragma unroll
        for (int it = 0; it < 16; ++it) {
            int off = it * 8192 + tid * 16;
            *(bf16x8*)(smem + off) = *(const bf16x8*)(Wl + off);
        }
        const int unit = cb * 8 + nt * 4 + lhi;
        const float bia0 = bip[l * 1024 + unit];
        const float bia1 = bfp[l * 1024 + unit];
        const float bia2 = bcp[l * 1024 + unit];
        const float bia3 = bop[l * 1024 + unit];
        float creg = 0.f;
        __syncthreads();                           // slab staged

        f32x4 acc0 = {}, acc1 = {};
        {   // x-part for t = 0 (A = x-frags nt*32+kt, B = x rows)
            const __bf16* xb = inp + (size_t)row * Hn + lhi * 8;
#pragma unroll
            for (int kt = 0; kt < 32; kt += 2) {
                bf16x8 a0 = *(const bf16x8*)(smem + (unsigned)((nt * 32 + kt) << 10) + lane16);
                bf16x8 a1 = *(const bf16x8*)(smem + (unsigned)((nt * 32 + kt + 1) << 10) + lane16);
                bf16x8 b0 = *(const bf16x8*)(xb + kt * 32);
                bf16x8 b1 = *(const bf16x8*)(xb + kt * 32 + 32);
                acc0 = MFMA16(a0, b0, acc0);
                acc1 = MFMA16(a1, b1, acc1);
            }
        }

        for (int t = 0; t < Tn; ++t) {
            if (t > 0) {
                pollwait(pollp, (unsigned)(l * Tn + t));
                // h-part: A = h-frags (2+nt)*32+kt from LDS, B = h[t-1] rows
                // (normal cached loads; L2/L3 broadcast)
                const __bf16* hb = outp + ((size_t)(t - 1) * Bn + row) * Hn + lhi * 8;
#pragma unroll
                for (int kt = 0; kt < 32; kt += 2) {
                    bf16x8 a0 = *(const bf16x8*)(smem + (unsigned)(((2 + nt) * 32 + kt) << 10) + lane16);
                    bf16x8 a1 = *(const bf16x8*)(smem + (unsigned)(((2 + nt) * 32 + kt + 1) << 10) + lane16);
                    bf16x8 b0 = *(const bf16x8*)(hb + kt * 32);
                    bf16x8 b1 = *(const bf16x8*)(hb + kt * 32 + 32);
                    acc0 = MFMA16(a0, b0, acc0);
                    acc1 = MFMA16(a1, b1, acc1);
                }
            }
            // ---- lane-local epilogue: acc[j] = gate j for (row, unit)
            float zi = acc0[0] + acc1[0] + bia0;
            float zf = acc0[1] + acc1[1] + bia1;
            float zg = acc0[2] + acc1[2] + bia2;
            float zo = acc0[3] + acc1[3] + bia3;
            float ii = fsigmoid(zi);
            float ff = fsigmoid(zf);
            float gg = ftanh(zg);
            float oo = fsigmoid(zo);
            creg = creg * ff + ii * gg;
            float hv = oo * ftanh(creg);
            // pack 4 units of one row (lhi 0..3) -> dwordx2 at lanes < 16
            unsigned hb16 = (unsigned)__builtin_bit_cast(unsigned short, (__bf16)hv);
            unsigned d = hb16 | ((unsigned)__shfl_xor((int)hb16, 16) << 16);
            unsigned e = (unsigned)__shfl_xor((int)d, 32);
            if (lane < 16) {
                u32x2 v2 = {d, e};
                store_coh_u32x2(outp + ((size_t)t * Bn + row) * Hn + cb * 8 + nt * 4, v2);
            }
            // NOTHING between store-drain and flag (r11 lesson)
            asm volatile("s_waitcnt vmcnt(0)" ::: "memory");   // h at L3
            if (lane == 0)
                store_coh_u16(myflag, (unsigned)(l * Tn + t + 1));
            // ---- x-part for t+1 (post-flag; hides next poll interval)
            acc0 = (f32x4){}; acc1 = (f32x4){};
            if (t < Tn - 1) {
                const __bf16* xb = inp + ((size_t)(t + 1) * Bn + row) * Hn + lhi * 8;
#pragma unroll
                for (int kt = 0; kt < 32; kt += 2) {
                    bf16x8 a0 = *(const bf16x8*)(smem + (unsigned)((nt * 32 + kt) << 10) + lane16);
                    bf16x8 a1 = *(const bf16x8*)(smem + (unsigned)((nt * 32 + kt + 1) << 10) + lane16);
                    bf16x8 b0 = *(const bf16x8*)(xb + kt * 32);
                    bf16x8 b1 = *(const bf16x8*)(xb + kt * 32 + 32);
                    acc0 = MFMA16(a0, b0, acc0);
                    acc1 = MFMA16(a1, b1, acc1);
                }
            }
        }
        __bf16* tmp = outp; outp = inp; inp = tmp; // ping-pong
    }
}

// ---------------------------------------------------------------------------
// out[b] = dot(h5[T-1][b][:], Wfc) + bfc
__global__ void fc_kernel(const __bf16* __restrict__ seq, const float* __restrict__ Wfc,
                          const float* __restrict__ bfc, float* __restrict__ out) {
    int b = blockIdx.x;
    int tid = threadIdx.x;
    const __bf16* h = seq + ((size_t)(Tn - 1) * Bn + b) * Hn;
    float s = 0.f;
    for (int k = tid; k < Hn; k += 256) s += (float)h[k] * Wfc[k];
#pragma unroll
    for (int off = 32; off > 0; off >>= 1) s += __shfl_down(s, off);
    __shared__ float red[4];
    if ((tid & 63) == 0) red[tid >> 6] = s;
    __syncthreads();
    if (tid == 0) out[b] = red[0] + red[1] + red[2] + red[3] + bfc[0];
}

// ---------------------------------------------------------------------------
extern "C" void kernel_launch(void* const* d_in, const int* in_sizes, int n_in,
                              void* d_out, int out_size, void* d_ws, size_t ws_size,
                              hipStream_t stream) {
    const float* x   = (const float*)d_in[0];
    const float* Wi  = (const float*)d_in[1];
    const float* bi  = (const float*)d_in[2];
    const float* Wf  = (const float*)d_in[3];
    const float* bf  = (const float*)d_in[4];
    const float* Wc  = (const float*)d_in[5];
    const float* bc  = (const float*)d_in[6];
    const float* Wo  = (const float*)d_in[7];
    const float* bo  = (const float*)d_in[8];
    const float* Wfc = (const float*)d_in[9];
    const float* bfc = (const float*)d_in[10];

    char* ws = (char*)d_ws;
    __bf16*         Wperm = (__bf16*)ws;                               // 83,886,080 B
    __bf16*         seqA  = (__bf16*)(ws + 83886080);                  // 33,554,432 B
    __bf16*         seqB  = (__bf16*)(ws + 83886080 + 33554432);       // 33,554,432 B
    unsigned short* bar   = (unsigned short*)(ws + 83886080 + 2 * 33554432); // 2,048 B

    hipFuncSetAttribute((const void*)lstm_all,
                        hipFuncAttributeMaxDynamicSharedMemorySize, 131072);

    hipLaunchKernelGGL(convW, dim3(20480), dim3(256), 0, stream, Wi, Wf, Wc, Wo, Wperm);
    hipLaunchKernelGGL(convX, dim3(8192), dim3(256), 0, stream, x, seqA);
    hipMemsetAsync(bar, 0, 2048, stream);
    hipMemsetAsync(seqB, 0, 33554432, stream);  // sentinel: "didn't run" => exact-ref absmax

    void* args[] = {(void*)&seqA, (void*)&seqB, (void*)&Wperm,
                    (void*)&bi, (void*)&bf, (void*)&bc, (void*)&bo, (void*)&bar};
    hipError_t ce = hipLaunchCooperativeKernel((const void*)lstm_all, dim3(128),
                                               dim3(512), args, 131072, stream);
    if (ce != hipSuccess) {
        // fallback: plain launch. 128 blocks <= 256 CUs at 1 block/CU, all
        // co-resident; flag protocol can't deadlock.
        hipLaunchKernelGGL(lstm_all, dim3(128), dim3(512), 131072, stream,
                           seqA, seqB, (const __bf16*)Wperm, bi, bf, bc, bo, bar);
    }

    // after 5 ping-pongs the final hidden sequence is in seqB
    hipLaunchKernelGGL(fc_kernel, dim3(64), dim3(256), 0, stream, seqB, Wfc, bfc,
                       (float*)d_out);
}

// Round 13
// 9143.546 us; speedup vs baseline: 2.0283x; 2.0283x over previous
//
#include <hip/hip_runtime.h>
#include <hip/hip_bf16.h>

// 5-layer LSTM, B=64, T=256, H=1024. bf16 MFMA (16x16x32), fp32 state.
// Round 13: 2-group LAYER PIPELINE (~770 serial hops instead of 1280).
//  Group A (even bids): layers 0 -> 2 -> 4; group B (odd bids): 1 -> 3.
//  Block = half-batch (32 rows) x 16 units; 8 waves = 2kg x 2mg x 2ns.
//  h-weights LDS-resident (128 KiB); x-weights streamed from L2 in shadow.
//  r6 protocol: sc0sc1 stores + per-wave drain + u16 flags + cached reads
//  + per-layer acquire fence. Buffers X->A->B->X->A->B (causally safe).

using bf16x8 = __attribute__((ext_vector_type(8))) __bf16;
using f32x4  = __attribute__((ext_vector_type(4))) float;
using u32x4  = __attribute__((ext_vector_type(4))) unsigned;

#define Tn 256
#define Bn 64
#define Hn 1024

#define MFMA16(a, b, c) __builtin_amdgcn_mfma_f32_16x16x32_bf16((a), (b), (c), 0, 0, 0)

// ---------------------------------------------------------------------------
// Wg[l][k][unit] fp32 -> Wperm B-frag-linear bf16.
// Per (l, cb16): a 256 KiB slab of 256 frags x 64 lanes x 16 B.
// frag = ((p*2+kg)*16+kt)*4 + g   (p: 0=x,1=h; kg: K-half; kt: K/32; g: gate)
// lane = lhi*16 + u16; element (col = g*16+u16 -> tile nf=g, l15=u16;
// k = p*1024 + kg*512 + kt*32 + lhi*8 + j)
__global__ void convW(const float* __restrict__ Wi, const float* __restrict__ Wf,
                      const float* __restrict__ Wc, const float* __restrict__ Wo,
                      __bf16* __restrict__ Wperm) {
    int gid = blockIdx.x * 256 + threadIdx.x;      // 5*1024*4*256 = 5,242,880
    int k8   = gid & 255;                          // k = k8*8 + j
    int g    = (gid >> 8) & 3;
    int unit = (gid >> 10) & 1023;
    int l    = gid >> 20;
    const float* Wg = (g == 0) ? Wi : (g == 1) ? Wf : (g == 2) ? Wc : Wo;
    const float* src = Wg + ((size_t)l * 2048 + k8 * 8) * 1024 + unit;
    bf16x8 v;
#pragma unroll
    for (int j = 0; j < 8; ++j) v[j] = (__bf16)src[(size_t)j * 1024];
    int cb16 = unit >> 4, u16 = unit & 15;
    int p = k8 >> 7, kg = (k8 >> 6) & 1, kt = (k8 >> 2) & 15, lh = k8 & 3;
    int frag = ((p * 2 + kg) * 16 + kt) * 4 + g;
    int lane = lh * 16 + u16;
    size_t dst = ((size_t)(l * 64 + cb16) * 256 + frag) * 1024 + (size_t)lane * 16;
    *(bf16x8*)((char*)Wperm + dst) = v;
}

// x[b][t][k] fp32 -> seq[t][b][k] bf16
__global__ void convX(const float* __restrict__ x, __bf16* __restrict__ seq) {
    int gid = blockIdx.x * 256 + threadIdx.x;      // 2,097,152
    int k8 = gid & 127;
    int b  = (gid >> 7) & 63;
    int t  = gid >> 13;
    const float* src = x + ((size_t)b * Tn + t) * Hn + k8 * 8;
    bf16x8 v;
#pragma unroll
    for (int j = 0; j < 8; ++j) v[j] = (__bf16)src[j];
    *(bf16x8*)(seq + (size_t)gid * 8) = v;
}

// ---------------------------------------------------------------------------
__device__ __forceinline__ void store_coh_u32x4(void* p, u32x4 v) {
    asm volatile("global_store_dwordx4 %0, %1, off sc0 sc1" :: "v"(p), "v"(v) : "memory");
}
__device__ __forceinline__ void store_coh_u16(void* p, unsigned v) {
    asm volatile("global_store_short %0, %1, off sc0 sc1" :: "v"(p), "v"(v) : "memory");
}
// poll 128 u16 flags (2 per lane, one dword); first try sleep-free
__device__ __forceinline__ void pollwait2(const char* p, unsigned target) {
    while (true) {
        unsigned v;
        asm volatile("global_load_dword %0, %1, off sc0 sc1\n\ts_waitcnt vmcnt(0)"
                     : "=&v"(v) : "v"(p) : "memory");
        bool ok = ((v & 0xFFFFu) >= target) && ((v >> 16) >= target);
        if (__all((int)ok)) break;
        __builtin_amdgcn_s_sleep(1);
    }
}
__device__ __forceinline__ float fsigmoid(float z) {
    return __builtin_amdgcn_rcpf(1.f + __builtin_amdgcn_exp2f(-1.44269504089f * z));
}
__device__ __forceinline__ float ftanh(float z) {
    return 1.f - 2.f * __builtin_amdgcn_rcpf(1.f + __builtin_amdgcn_exp2f(2.88539008178f * z));
}

// ---------------------------------------------------------------------------
// Persistent pipeline kernel. 256 blocks x 512 threads, 1 block/CU.
// g_self = bid&1 (0 = group A: layers 0,2,4; 1 = group B: layers 1,3).
// gbid = bid>>1: rb = gbid&1 (batch half), cb16 = gbid>>1 (16 units).
// Wave w: kg = w&1 (K-half 512), mg = (w>>1)&1 (16 rows), ns = w>>2 (2 gates).
// Lane: l15 = batch-row offset / unit col; lhi = k sub-offset.
// Epilogue: all 512 threads, thread = (row32 = (tid>>4)&31, u16 = tid&15).
// Flags: u16 idx = ((g*2+rb)*8 + w)*64 + cb16; value = l*256 + t + 1.
// Consumer (kg,mg) polls w in [4mg,4mg+4) x cb16 in [32kg,+32): 128 u16.
// LDS: [0,131072) h-weight frags; [131072,148480) zp [2][32][68] f32.
__global__ __launch_bounds__(512, 2) void lstm_pipe(
    __bf16* __restrict__ bufX, __bf16* __restrict__ bufA,
    __bf16* __restrict__ bufB, const __bf16* __restrict__ Wperm,
    const float* __restrict__ bip, const float* __restrict__ bfp,
    const float* __restrict__ bcp, const float* __restrict__ bop,
    unsigned short* __restrict__ bar) {
    extern __shared__ char smem[];
    float* zp = (float*)(smem + 131072);

    const int tid  = threadIdx.x;
    const int bid  = blockIdx.x;
    const int g_self = bid & 1;
    const int gbid = bid >> 1;
    const int rb   = gbid & 1;
    const int cb16 = gbid >> 1;                    // 0..63
    const int w    = tid >> 6;
    const int lane = tid & 63;
    const int kg   = w & 1;
    const int mg   = (w >> 1) & 1;
    const int ns   = w >> 2;                       // 0..1
    const int l15  = lane & 15;
    const int lhi  = lane >> 4;
    const int arow = rb * 32 + mg * 16 + l15;
    const unsigned lane16 = (unsigned)lane << 4;
    const int u16t  = tid & 15;
    const int row32 = (tid >> 4) & 31;

    unsigned short* myflag = bar + (((g_self * 2 + rb) * 8 + w) * 64 + cb16);
    const char* pollin = (const char*)bar +
        ((((g_self * 2 + rb) * 8 + 4 * mg + lhi) * 64) + kg * 32 + 2 * l15) * 2;
    const char* pollup = (const char*)bar +
        (((((1 - g_self) * 2 + rb) * 8 + 4 * mg + lhi) * 64) + kg * 32 + 2 * l15) * 2;

    __bf16* bin_[5]  = {bufX, bufA, bufB, bufX, bufA};
    __bf16* bout_[5] = {bufA, bufB, bufX, bufA, bufB};

    const int nl = (g_self == 0) ? 3 : 2;
    for (int s = 0; s < nl; ++s) {
        const int l = 2 * s + g_self;
        const int lbase = l << 8;
        const __bf16* xin = bin_[l];
        __bf16* hout = bout_[l];
        const char* WlG = (const char*)Wperm + (size_t)(l * 64 + cb16) * 262144;

        __syncthreads();                           // prev layer's LDS reads done
        __builtin_amdgcn_fence(__ATOMIC_ACQUIRE, "agent");  // inv L1/L2

        // stage h-part weight frags (second 128 KiB of slab) into LDS
#pragma unroll
        for (int it = 0; it < 16; ++it) {
            int off = it * 8192 + tid * 16;
            *(bf16x8*)(smem + off) = *(const bf16x8*)(WlG + 131072 + off);
        }
        const int unit = cb16 * 16 + u16t;
        const float bia0 = bip[(l << 10) + unit];
        const float bia1 = bfp[(l << 10) + unit];
        const float bia2 = bcp[(l << 10) + unit];
        const float bia3 = bop[(l << 10) + unit];
        float creg = 0.f;
        __syncthreads();                           // slab staged

        if (l > 0) pollwait2(pollup, (unsigned)(lbase - 256 + 1));  // h_{l-1}[0]
        f32x4 acc0 = {}, acc1 = {};
        {   // x-part for t = 0 (weights streamed from global/L2)
            const __bf16* xb = xin + (size_t)arow * Hn + kg * 512 + lhi * 8;
#pragma unroll
            for (int kt = 0; kt < 16; ++kt) {
                bf16x8 a  = *(const bf16x8*)(xb + kt * 32);
                bf16x8 b0 = *(const bf16x8*)(WlG + (unsigned)(((kg * 16 + kt) * 4 + 2 * ns) << 10) + lane16);
                bf16x8 b1 = *(const bf16x8*)(WlG + (unsigned)(((kg * 16 + kt) * 4 + 2 * ns + 1) << 10) + lane16);
                acc0 = MFMA16(a, b0, acc0);
                acc1 = MFMA16(a, b1, acc1);
            }
        }

        for (int t = 0; t < Tn; ++t) {
            if (t > 0) {
                pollwait2(pollin, (unsigned)(lbase + t));
                // h-part: acts normal-cached, weights from LDS
                const __bf16* hb = hout + ((size_t)(t - 1) * Bn + arow) * Hn + kg * 512 + lhi * 8;
#pragma unroll
                for (int kt = 0; kt < 16; ++kt) {
                    bf16x8 a  = *(const bf16x8*)(hb + kt * 32);
                    bf16x8 b0 = *(const bf16x8*)(smem + (unsigned)(((kg * 16 + kt) * 4 + 2 * ns) << 10) + lane16);
                    bf16x8 b1 = *(const bf16x8*)(smem + (unsigned)(((kg * 16 + kt) * 4 + 2 * ns + 1) << 10) + lane16);
                    acc0 = MFMA16(a, b0, acc0);
                    acc1 = MFMA16(a, b1, acc1);
                }
            }
            // publish partials: D row = 4*lhi+j, col-tile nf -> gate 2ns+nf
            {
                float* zw = zp + (kg * 32 + mg * 16 + 4 * lhi) * 68 + (2 * ns) * 16 + l15;
#pragma unroll
                for (int j = 0; j < 4; ++j) { zw[j * 68] = acc0[j]; zw[j * 68 + 16] = acc1[j]; }
            }
            __syncthreads();                       // sync1: zp ready
            const float* zr = zp + row32 * 68 + u16t;
            float z0 = bia0 + zr[0]  + zr[2176];   // + plane kg=1 (32*68)
            float z1 = bia1 + zr[16] + zr[2192];
            float z2 = bia2 + zr[32] + zr[2208];
            float z3 = bia3 + zr[48] + zr[2224];
            __syncthreads();                       // sync2: zp reads done
            float ii = fsigmoid(z0), ff = fsigmoid(z1);
            float gg = ftanh(z2),    oo = fsigmoid(z3);
            creg = creg * ff + ii * gg;
            float hv = oo * ftanh(creg);
            // pack 8 units -> dwordx4 (lanes u16 % 8 == 0; 2 stores per row)
            unsigned hb16 = (unsigned)__builtin_bit_cast(unsigned short, (__bf16)hv);
            unsigned d  = hb16 | ((unsigned)__shfl_xor((int)hb16, 1) << 16);
            unsigned d2 = (unsigned)__shfl_xor((int)d, 2);
            unsigned e0 = (unsigned)__shfl_xor((int)d, 4);
            unsigned e1 = (unsigned)__shfl_xor((int)d2, 4);
            if ((lane & 7) == 0) {
                u32x4 v4 = {d, d2, e0, e1};
                store_coh_u32x4(hout + ((size_t)t * Bn + rb * 32 + row32) * Hn
                                     + cb16 * 16 + u16t, v4);
            }
            asm volatile("s_waitcnt vmcnt(0)" ::: "memory");  // own rows at L3
            if (lane == 0)
                store_coh_u16(myflag, (unsigned)(lbase + t + 1));
            // shadow: x-part for t+1 (needs upstream h_{l-1}[t+1])
            acc0 = (f32x4){}; acc1 = (f32x4){};
            if (t < Tn - 1) {
                if (l > 0) pollwait2(pollup, (unsigned)(lbase - 256 + t + 2));
                const __bf16* xb = xin + ((size_t)(t + 1) * Bn + arow) * Hn + kg * 512 + lhi * 8;
#pragma unroll
                for (int kt = 0; kt < 16; ++kt) {
                    bf16x8 a  = *(const bf16x8*)(xb + kt * 32);
                    bf16x8 b0 = *(const bf16x8*)(WlG + (unsigned)(((kg * 16 + kt) * 4 + 2 * ns) << 10) + lane16);
                    bf16x8 b1 = *(const bf16x8*)(WlG + (unsigned)(((kg * 16 + kt) * 4 + 2 * ns + 1) << 10) + lane16);
                    acc0 = MFMA16(a, b0, acc0);
                    acc1 = MFMA16(a, b1, acc1);
                }
            }
        }
    }
}

// ---------------------------------------------------------------------------
// out[b] = dot(h5[T-1][b][:], Wfc) + bfc
__global__ void fc_kernel(const __bf16* __restrict__ seq, const float* __restrict__ Wfc,
                          const float* __restrict__ bfc, float* __restrict__ out) {
    int b = blockIdx.x;
    int tid = threadIdx.x;
    const __bf16* h = seq + ((size_t)(Tn - 1) * Bn + b) * Hn;
    float s = 0.f;
    for (int k = tid; k < Hn; k += 256) s += (float)h[k] * Wfc[k];
#pragma unroll
    for (int off = 32; off > 0; off >>= 1) s += __shfl_down(s, off);
    __shared__ float red[4];
    if ((tid & 63) == 0) red[tid >> 6] = s;
    __syncthreads();
    if (tid == 0) out[b] = red[0] + red[1] + red[2] + red[3] + bfc[0];
}

// ---------------------------------------------------------------------------
extern "C" void kernel_launch(void* const* d_in, const int* in_sizes, int n_in,
                              void* d_out, int out_size, void* d_ws, size_t ws_size,
                              hipStream_t stream) {
    const float* x   = (const float*)d_in[0];
    const float* Wi  = (const float*)d_in[1];
    const float* bi  = (const float*)d_in[2];
    const float* Wf  = (const float*)d_in[3];
    const float* bf  = (const float*)d_in[4];
    const float* Wc  = (const float*)d_in[5];
    const float* bc  = (const float*)d_in[6];
    const float* Wo  = (const float*)d_in[7];
    const float* bo  = (const float*)d_in[8];
    const float* Wfc = (const float*)d_in[9];
    const float* bfc = (const float*)d_in[10];

    char* ws = (char*)d_ws;
    __bf16*         Wperm = (__bf16*)ws;                         // 83,886,080 B
    __bf16*         bufX  = (__bf16*)(ws + 83886080);            // 33,554,432 B
    __bf16*         bufA  = (__bf16*)(ws + 117440512);           // 33,554,432 B
    __bf16*         bufB  = (__bf16*)(ws + 150994944);           // 33,554,432 B
    unsigned short* bar   = (unsigned short*)(ws + 184549376);   //      4,096 B

    if (ws_size < 184553472) return;  // ws too small: leave zeros (diagnosable)

    hipFuncSetAttribute((const void*)lstm_pipe,
                        hipFuncAttributeMaxDynamicSharedMemorySize, 148480);

    hipLaunchKernelGGL(convW, dim3(20480), dim3(256), 0, stream, Wi, Wf, Wc, Wo, Wperm);
    hipLaunchKernelGGL(convX, dim3(8192), dim3(256), 0, stream, x, bufX);
    hipMemsetAsync(bar, 0, 4096, stream);

    void* args[] = {(void*)&bufX, (void*)&bufA, (void*)&bufB, (void*)&Wperm,
                    (void*)&bi, (void*)&bf, (void*)&bc, (void*)&bo, (void*)&bar};
    hipError_t ce = hipLaunchCooperativeKernel((const void*)lstm_pipe, dim3(256),
                                               dim3(512), args, 148480, stream);
    if (ce != hipSuccess) {
        // fallback: plain launch; 256 blocks co-resident at 1 block/CU, so
        // the flag protocol cannot deadlock.
        hipLaunchKernelGGL(lstm_pipe, dim3(256), dim3(512), 148480, stream,
                           bufX, bufA, bufB, (const __bf16*)Wperm,
                           bi, bf, bc, bo, bar);
    }

    // l4 output lives in bufB
    hipLaunchKernelGGL(fc_kernel, dim3(64), dim3(256), 0, stream, bufB, Wfc, bfc,
                       (float*)d_out);
}

// Round 14
// 9135.873 us; speedup vs baseline: 2.0300x; 1.0008x over previous
//
#include <hip/hip_runtime.h>
#include <hip/hip_bf16.h>

// 5-layer LSTM, B=64, T=256, H=1024. bf16 MFMA (16x16x32), fp32 state.
// Round 14: r13 2-group layer pipeline (~770 hops, protocol verified) with
// XCD-LOCALIZED block->(g,rb,cb16) mapping:
//   xcd = bid&7, slot = bid>>3; cb16 = xcd*8 + (slot&7); rb=(slot>>3)&1;
//   g = slot>>4.  Per XCD: 8 cb16 x 2 groups = 16 x-weight slabs = 2 MB,
//   L2-resident -> shadow x-GEMM weight loads become L2 hits (r13: HBM
//   misses at 1.22 TB/s were serialized into every hop).

using bf16x8 = __attribute__((ext_vector_type(8))) __bf16;
using f32x4  = __attribute__((ext_vector_type(4))) float;
using u32x4  = __attribute__((ext_vector_type(4))) unsigned;

#define Tn 256
#define Bn 64
#define Hn 1024

#define MFMA16(a, b, c) __builtin_amdgcn_mfma_f32_16x16x32_bf16((a), (b), (c), 0, 0, 0)

// ---------------------------------------------------------------------------
// Wg[l][k][unit] fp32 -> Wperm B-frag-linear bf16.
// Per (l, cb16): a 256 KiB slab of 256 frags x 64 lanes x 16 B.
// frag = ((p*2+kg)*16+kt)*4 + g   (p: 0=x,1=h; kg: K-half; kt: K/32; g: gate)
// lane = lhi*16 + u16; element (col = g*16+u16, k = p*1024+kg*512+kt*32+lhi*8+j)
__global__ void convW(const float* __restrict__ Wi, const float* __restrict__ Wf,
                      const float* __restrict__ Wc, const float* __restrict__ Wo,
                      __bf16* __restrict__ Wperm) {
    int gid = blockIdx.x * 256 + threadIdx.x;      // 5*1024*4*256 = 5,242,880
    int k8   = gid & 255;                          // k = k8*8 + j
    int g    = (gid >> 8) & 3;
    int unit = (gid >> 10) & 1023;
    int l    = gid >> 20;
    const float* Wg = (g == 0) ? Wi : (g == 1) ? Wf : (g == 2) ? Wc : Wo;
    const float* src = Wg + ((size_t)l * 2048 + k8 * 8) * 1024 + unit;
    bf16x8 v;
#pragma unroll
    for (int j = 0; j < 8; ++j) v[j] = (__bf16)src[(size_t)j * 1024];
    int cb16 = unit >> 4, u16 = unit & 15;
    int p = k8 >> 7, kg = (k8 >> 6) & 1, kt = (k8 >> 2) & 15, lh = k8 & 3;
    int frag = ((p * 2 + kg) * 16 + kt) * 4 + g;
    int lane = lh * 16 + u16;
    size_t dst = ((size_t)(l * 64 + cb16) * 256 + frag) * 1024 + (size_t)lane * 16;
    *(bf16x8*)((char*)Wperm + dst) = v;
}

// x[b][t][k] fp32 -> seq[t][b][k] bf16
__global__ void convX(const float* __restrict__ x, __bf16* __restrict__ seq) {
    int gid = blockIdx.x * 256 + threadIdx.x;      // 2,097,152
    int k8 = gid & 127;
    int b  = (gid >> 7) & 63;
    int t  = gid >> 13;
    const float* src = x + ((size_t)b * Tn + t) * Hn + k8 * 8;
    bf16x8 v;
#pragma unroll
    for (int j = 0; j < 8; ++j) v[j] = (__bf16)src[j];
    *(bf16x8*)(seq + (size_t)gid * 8) = v;
}

// ---------------------------------------------------------------------------
__device__ __forceinline__ void store_coh_u32x4(void* p, u32x4 v) {
    asm volatile("global_store_dwordx4 %0, %1, off sc0 sc1" :: "v"(p), "v"(v) : "memory");
}
__device__ __forceinline__ void store_coh_u16(void* p, unsigned v) {
    asm volatile("global_store_short %0, %1, off sc0 sc1" :: "v"(p), "v"(v) : "memory");
}
// poll 128 u16 flags (2 per lane, one dword); first try sleep-free
__device__ __forceinline__ void pollwait2(const char* p, unsigned target) {
    while (true) {
        unsigned v;
        asm volatile("global_load_dword %0, %1, off sc0 sc1\n\ts_waitcnt vmcnt(0)"
                     : "=&v"(v) : "v"(p) : "memory");
        bool ok = ((v & 0xFFFFu) >= target) && ((v >> 16) >= target);
        if (__all((int)ok)) break;
        __builtin_amdgcn_s_sleep(1);
    }
}
__device__ __forceinline__ float fsigmoid(float z) {
    return __builtin_amdgcn_rcpf(1.f + __builtin_amdgcn_exp2f(-1.44269504089f * z));
}
__device__ __forceinline__ float ftanh(float z) {
    return 1.f - 2.f * __builtin_amdgcn_rcpf(1.f + __builtin_amdgcn_exp2f(2.88539008178f * z));
}

// ---------------------------------------------------------------------------
// Persistent pipeline kernel. 256 blocks x 512 threads, 1 block/CU.
// XCD-localized decode: xcd = bid&7, slot = bid>>3;
//   cb16 = xcd*8 + (slot&7); rb = (slot>>3)&1; g_self = slot>>4.
// Group A (g=0): layers 0,2,4; group B (g=1): layers 1,3.
// Wave w: kg = w&1 (K-half 512), mg = (w>>1)&1 (16 rows), ns = w>>2 (2 gates).
// Epilogue: all 512 threads, thread = (row32 = (tid>>4)&31, u16 = tid&15).
// Flags: u16 idx = ((g*2+rb)*8 + w)*64 + cb16; value = l*256 + t + 1.
// LDS: [0,131072) h-weight frags; [131072,148480) zp [2][32][68] f32.
__global__ __launch_bounds__(512, 2) void lstm_pipe(
    __bf16* __restrict__ bufX, __bf16* __restrict__ bufA,
    __bf16* __restrict__ bufB, const __bf16* __restrict__ Wperm,
    const float* __restrict__ bip, const float* __restrict__ bfp,
    const float* __restrict__ bcp, const float* __restrict__ bop,
    unsigned short* __restrict__ bar) {
    extern __shared__ char smem[];
    float* zp = (float*)(smem + 131072);

    const int tid  = threadIdx.x;
    const int bid  = blockIdx.x;
    const int xcd  = bid & 7;
    const int slot = bid >> 3;                     // 0..31
    const int cb16 = xcd * 8 + (slot & 7);         // 0..63, 8 per XCD
    const int rb   = (slot >> 3) & 1;
    const int g_self = slot >> 4;                  // 0..1
    const int w    = tid >> 6;
    const int lane = tid & 63;
    const int kg   = w & 1;
    const int mg   = (w >> 1) & 1;
    const int ns   = w >> 2;                       // 0..1
    const int l15  = lane & 15;
    const int lhi  = lane >> 4;
    const int arow = rb * 32 + mg * 16 + l15;
    const unsigned lane16 = (unsigned)lane << 4;
    const int u16t  = tid & 15;
    const int row32 = (tid >> 4) & 31;

    unsigned short* myflag = bar + (((g_self * 2 + rb) * 8 + w) * 64 + cb16);
    const char* pollin = (const char*)bar +
        ((((g_self * 2 + rb) * 8 + 4 * mg + lhi) * 64) + kg * 32 + 2 * l15) * 2;
    const char* pollup = (const char*)bar +
        (((((1 - g_self) * 2 + rb) * 8 + 4 * mg + lhi) * 64) + kg * 32 + 2 * l15) * 2;

    __bf16* bin_[5]  = {bufX, bufA, bufB, bufX, bufA};
    __bf16* bout_[5] = {bufA, bufB, bufX, bufA, bufB};

    const int nl = (g_self == 0) ? 3 : 2;
    for (int s = 0; s < nl; ++s) {
        const int l = 2 * s + g_self;
        const int lbase = l << 8;
        const __bf16* xin = bin_[l];
        __bf16* hout = bout_[l];
        const char* WlG = (const char*)Wperm + (size_t)(l * 64 + cb16) * 262144;

        __syncthreads();                           // prev layer's LDS reads done
        __builtin_amdgcn_fence(__ATOMIC_ACQUIRE, "agent");  // inv L1/L2

        // stage h-part weight frags (second 128 KiB of slab) into LDS
#pragma unroll
        for (int it = 0; it < 16; ++it) {
            int off = it * 8192 + tid * 16;
            *(bf16x8*)(smem + off) = *(const bf16x8*)(WlG + 131072 + off);
        }
        const int unit = cb16 * 16 + u16t;
        const float bia0 = bip[(l << 10) + unit];
        const float bia1 = bfp[(l << 10) + unit];
        const float bia2 = bcp[(l << 10) + unit];
        const float bia3 = bop[(l << 10) + unit];
        float creg = 0.f;
        __syncthreads();                           // slab staged

        if (l > 0) pollwait2(pollup, (unsigned)(lbase - 256 + 1));  // h_{l-1}[0]
        f32x4 acc0 = {}, acc1 = {};
        {   // x-part for t = 0 (weights from L2 after remap)
            const __bf16* xb = xin + (size_t)arow * Hn + kg * 512 + lhi * 8;
#pragma unroll
            for (int kt = 0; kt < 16; ++kt) {
                bf16x8 a  = *(const bf16x8*)(xb + kt * 32);
                bf16x8 b0 = *(const bf16x8*)(WlG + (unsigned)(((kg * 16 + kt) * 4 + 2 * ns) << 10) + lane16);
                bf16x8 b1 = *(const bf16x8*)(WlG + (unsigned)(((kg * 16 + kt) * 4 + 2 * ns + 1) << 10) + lane16);
                acc0 = MFMA16(a, b0, acc0);
                acc1 = MFMA16(a, b1, acc1);
            }
        }

        for (int t = 0; t < Tn; ++t) {
            if (t > 0) {
                pollwait2(pollin, (unsigned)(lbase + t));
                // h-part: acts normal-cached, weights from LDS
                const __bf16* hb = hout + ((size_t)(t - 1) * Bn + arow) * Hn + kg * 512 + lhi * 8;
#pragma unroll
                for (int kt = 0; kt < 16; ++kt) {
                    bf16x8 a  = *(const bf16x8*)(hb + kt * 32);
                    bf16x8 b0 = *(const bf16x8*)(smem + (unsigned)(((kg * 16 + kt) * 4 + 2 * ns) << 10) + lane16);
                    bf16x8 b1 = *(const bf16x8*)(smem + (unsigned)(((kg * 16 + kt) * 4 + 2 * ns + 1) << 10) + lane16);
                    acc0 = MFMA16(a, b0, acc0);
                    acc1 = MFMA16(a, b1, acc1);
                }
            }
            // publish partials: D row = 4*lhi+j, col-tile nf -> gate 2ns+nf
            {
                float* zw = zp + (kg * 32 + mg * 16 + 4 * lhi) * 68 + (2 * ns) * 16 + l15;
#pragma unroll
                for (int j = 0; j < 4; ++j) { zw[j * 68] = acc0[j]; zw[j * 68 + 16] = acc1[j]; }
            }
            __syncthreads();                       // sync1: zp ready
            const float* zr = zp + row32 * 68 + u16t;
            float z0 = bia0 + zr[0]  + zr[2176];   // + plane kg=1 (32*68)
            float z1 = bia1 + zr[16] + zr[2192];
            float z2 = bia2 + zr[32] + zr[2208];
            float z3 = bia3 + zr[48] + zr[2224];
            __syncthreads();                       // sync2: zp reads done
            float ii = fsigmoid(z0), ff = fsigmoid(z1);
            float gg = ftanh(z2),    oo = fsigmoid(z3);
            creg = creg * ff + ii * gg;
            float hv = oo * ftanh(creg);
            // pack 8 units -> dwordx4 (lanes u16 % 8 == 0; 2 stores per row)
            unsigned hb16 = (unsigned)__builtin_bit_cast(unsigned short, (__bf16)hv);
            unsigned d  = hb16 | ((unsigned)__shfl_xor((int)hb16, 1) << 16);
            unsigned d2 = (unsigned)__shfl_xor((int)d, 2);
            unsigned e0 = (unsigned)__shfl_xor((int)d, 4);
            unsigned e1 = (unsigned)__shfl_xor((int)d2, 4);
            if ((lane & 7) == 0) {
                u32x4 v4 = {d, d2, e0, e1};
                store_coh_u32x4(hout + ((size_t)t * Bn + rb * 32 + row32) * Hn
                                     + cb16 * 16 + u16t, v4);
            }
            asm volatile("s_waitcnt vmcnt(0)" ::: "memory");  // own rows at L3
            if (lane == 0)
                store_coh_u16(myflag, (unsigned)(lbase + t + 1));
            // shadow: x-part for t+1 (needs upstream h_{l-1}[t+1])
            acc0 = (f32x4){}; acc1 = (f32x4){};
            if (t < Tn - 1) {
                if (l > 0) pollwait2(pollup, (unsigned)(lbase - 256 + t + 2));
                const __bf16* xb = xin + ((size_t)(t + 1) * Bn + arow) * Hn + kg * 512 + lhi * 8;
#pragma unroll
                for (int kt = 0; kt < 16; ++kt) {
                    bf16x8 a  = *(const bf16x8*)(xb + kt * 32);
                    bf16x8 b0 = *(const bf16x8*)(WlG + (unsigned)(((kg * 16 + kt) * 4 + 2 * ns) << 10) + lane16);
                    bf16x8 b1 = *(const bf16x8*)(WlG + (unsigned)(((kg * 16 + kt) * 4 + 2 * ns + 1) << 10) + lane16);
                    acc0 = MFMA16(a, b0, acc0);
                    acc1 = MFMA16(a, b1, acc1);
                }
            }
        }
    }
}

// ---------------------------------------------------------------------------
// out[b] = dot(h5[T-1][b][:], Wfc) + bfc
__global__ void fc_kernel(const __bf16* __restrict__ seq, const float* __restrict__ Wfc,
                          const float* __restrict__ bfc, float* __restrict__ out) {
    int b = blockIdx.x;
    int tid = threadIdx.x;
    const __bf16* h = seq + ((size_t)(Tn - 1) * Bn + b) * Hn;
    float s = 0.f;
    for (int k = tid; k < Hn; k += 256) s += (float)h[k] * Wfc[k];
#pragma unroll
    for (int off = 32; off > 0; off >>= 1) s += __shfl_down(s, off);
    __shared__ float red[4];
    if ((tid & 63) == 0) red[tid >> 6] = s;
    __syncthreads();
    if (tid == 0) out[b] = red[0] + red[1] + red[2] + red[3] + bfc[0];
}

// ---------------------------------------------------------------------------
extern "C" void kernel_launch(void* const* d_in, const int* in_sizes, int n_in,
                              void* d_out, int out_size, void* d_ws, size_t ws_size,
                              hipStream_t stream) {
    const float* x   = (const float*)d_in[0];
    const float* Wi  = (const float*)d_in[1];
    const float* bi  = (const float*)d_in[2];
    const float* Wf  = (const float*)d_in[3];
    const float* bf  = (const float*)d_in[4];
    const float* Wc  = (const float*)d_in[5];
    const float* bc  = (const float*)d_in[6];
    const float* Wo  = (const float*)d_in[7];
    const float* bo  = (const float*)d_in[8];
    const float* Wfc = (const float*)d_in[9];
    const float* bfc = (const float*)d_in[10];

    char* ws = (char*)d_ws;
    __bf16*         Wperm = (__bf16*)ws;                         // 83,886,080 B
    __bf16*         bufX  = (__bf16*)(ws + 83886080);            // 33,554,432 B
    __bf16*         bufA  = (__bf16*)(ws + 117440512);           // 33,554,432 B
    __bf16*         bufB  = (__bf16*)(ws + 150994944);           // 33,554,432 B
    unsigned short* bar   = (unsigned short*)(ws + 184549376);   //      4,096 B

    if (ws_size < 184553472) return;  // ws too small: leave zeros (diagnosable)

    hipFuncSetAttribute((const void*)lstm_pipe,
                        hipFuncAttributeMaxDynamicSharedMemorySize, 148480);

    hipLaunchKernelGGL(convW, dim3(20480), dim3(256), 0, stream, Wi, Wf, Wc, Wo, Wperm);
    hipLaunchKernelGGL(convX, dim3(8192), dim3(256), 0, stream, x, bufX);
    hipMemsetAsync(bar, 0, 4096, stream);

    void* args[] = {(void*)&bufX, (void*)&bufA, (void*)&bufB, (void*)&Wperm,
                    (void*)&bi, (void*)&bf, (void*)&bc, (void*)&bo, (void*)&bar};
    hipError_t ce = hipLaunchCooperativeKernel((const void*)lstm_pipe, dim3(256),
                                               dim3(512), args, 148480, stream);
    if (ce != hipSuccess) {
        // fallback: plain launch; 256 blocks co-resident at 1 block/CU, so
        // the flag protocol cannot deadlock.
        hipLaunchKernelGGL(lstm_pipe, dim3(256), dim3(512), 148480, stream,
                           bufX, bufA, bufB, (const __bf16*)Wperm,
                           bi, bf, bc, bo, bar);
    }

    // l4 output lives in bufB
    hipLaunchKernelGGL(fc_kernel, dim3(64), dim3(256), 0, stream, bufB, Wfc, bfc,
                       (float*)d_out);
}